// Round 2
// baseline (879.946 us; speedup 1.0000x reference)
//
#include <hip/hip_runtime.h>
#include <stdint.h>

#define NN 16384
#define EE 8192
#define FT 64

typedef float v4f __attribute__((ext_vector_type(4)));

__device__ __forceinline__ uint32_t prm(uint32_t hi, uint32_t lo, uint32_t sel) {
  return __builtin_amdgcn_perm(hi, lo, sel);
}

// pack 4 floats -> 4 fp8 e4m3 bytes (byte0 = a .. byte3 = d)
__device__ __forceinline__ uint32_t pk4(float a, float b, float c, float d) {
  uint32_t lo = __builtin_amdgcn_cvt_pk_fp8_f32(a, b, 0, false);
  return __builtin_amdgcn_cvt_pk_fp8_f32(c, d, lo, true);
}

// async global->LDS, 16B per lane; LDS dest = wave-uniform base + lane*16
__device__ __forceinline__ void gl_lds16(const uint8_t* g, uint8_t* l) {
  __builtin_amdgcn_global_load_lds(
      (const __attribute__((address_space(1))) void*)g,
      (__attribute__((address_space(3))) void*)l, 16, 0, 0);
}

// ---------------------------------------------------------------------------
// K1: stream H (fp32) once -> rowsum, colsum, Hn8 [N][E] fp8, H8T [E][N] fp8.
// 64 n-rows x 256 e-cols per block; in-register 4x4 byte transpose (v_perm),
// staged through padded LDS. Rowsum: 2-step DPP shuffle (xor 1,2) -> per-
// 4-lane partials in LDS -> 64-thread reduce -> 1 atomic/row (replaces the
// old 6-step ds_swizzle chain per row).
// ---------------------------------------------------------------------------
__global__ __launch_bounds__(256) void k_prep_h(
    const float* __restrict__ H,
    uint8_t* __restrict__ Hn8,
    uint8_t* __restrict__ H8T,
    float* __restrict__ rowsum,
    float* __restrict__ colsum)
{
  __shared__ uint8_t T8[256 * 68];     // [e_local][64 n + 4 pad]
  __shared__ float csumL[256];
  __shared__ float rpart[64][17];      // [n_local][16 4-lane groups + pad]

  const int t    = threadIdx.x;
  const int lane = t & 63;
  const int wv   = t >> 6;
  const int e0   = blockIdx.x * 256;
  const int n0   = blockIdx.y * 64;

  csumL[t] = 0.f;
  __syncthreads();

  float cs0 = 0.f, cs1 = 0.f, cs2 = 0.f, cs3 = 0.f;

  for (int m = 0; m < 4; ++m) {
    const int g = wv + 4 * m;            // row-group 0..15 (wave-private)
    float4 r[4];
#pragma unroll
    for (int i = 0; i < 4; ++i) {
      const float* p = H + (size_t)(n0 + 4 * g + i) * EE + e0 + 4 * lane;
      r[i] = *(const float4*)p;
    }
    uint32_t D[4];
#pragma unroll
    for (int i = 0; i < 4; ++i) {
      cs0 += r[i].x; cs1 += r[i].y; cs2 += r[i].z; cs3 += r[i].w;
      float rsv = r[i].x + r[i].y + r[i].z + r[i].w;
      rsv += __shfl_xor(rsv, 1);         // quad-perm DPP (VALU, not LDS)
      rsv += __shfl_xor(rsv, 2);
      if ((lane & 3) == 0) rpart[4 * g + i][lane >> 2] = rsv;
      D[i] = pk4(r[i].x, r[i].y, r[i].z, r[i].w);
      *(uint32_t*)(Hn8 + (size_t)(n0 + 4 * g + i) * EE + e0 + 4 * lane) = D[i];
    }
    uint32_t lo01 = prm(D[1], D[0], 0x05010400u);
    uint32_t hi01 = prm(D[1], D[0], 0x07030602u);
    uint32_t lo23 = prm(D[3], D[2], 0x05010400u);
    uint32_t hi23 = prm(D[3], D[2], 0x07030602u);
    uint32_t T0 = prm(lo23, lo01, 0x05040100u);
    uint32_t T1 = prm(lo23, lo01, 0x07060302u);
    uint32_t T2 = prm(hi23, hi01, 0x05040100u);
    uint32_t T3 = prm(hi23, hi01, 0x07060302u);
    *(uint32_t*)&T8[(size_t)(4 * lane + 0) * 68 + 4 * g] = T0;
    *(uint32_t*)&T8[(size_t)(4 * lane + 1) * 68 + 4 * g] = T1;
    *(uint32_t*)&T8[(size_t)(4 * lane + 2) * 68 + 4 * g] = T2;
    *(uint32_t*)&T8[(size_t)(4 * lane + 3) * 68 + 4 * g] = T3;
  }

  atomicAdd(&csumL[4 * lane + 0], cs0);
  atomicAdd(&csumL[4 * lane + 1], cs1);
  atomicAdd(&csumL[4 * lane + 2], cs2);
  atomicAdd(&csumL[4 * lane + 3], cs3);
  __syncthreads();
  atomicAdd(&colsum[e0 + t], csumL[t]);

  // rowsum reduce: 64 threads, one row each, 16 partials -> 1 atomic
  if (t < 64) {
    float s = 0.f;
#pragma unroll
    for (int j = 0; j < 16; ++j) s += rpart[t][j];
    atomicAdd(&rowsum[n0 + t], s);
  }

  // H8T writeout: thread t -> (e_local = t>>2 + 64*jj, 16B n-chunk t&3);
  // 4 consecutive lanes = 64B contiguous per row.
  const int ec = t >> 2;
  const int nc = (t & 3) * 16;
#pragma unroll
  for (int jj = 0; jj < 4; ++jj) {
    const int el = ec + 64 * jj;
    uint4 v = *(const uint4*)&T8[(size_t)el * 68 + nc];
    *(uint4*)(H8T + (size_t)(e0 + el) * NN + n0 + nc) = v;
  }
}

// ---------------------------------------------------------------------------
// K2: Zt[f][n] = fp8( 64 * rsqrt(rowsum[n]) * (x @ weight)[n][f] )
// ---------------------------------------------------------------------------
__global__ __launch_bounds__(256) void k_z(
    const float* __restrict__ x,
    const float* __restrict__ weight,
    const float* __restrict__ rowsum,
    uint8_t* __restrict__ Zt)
{
  __shared__ float wT[64 * 68];
  const int t  = threadIdx.x;
  const int n0 = blockIdx.x * 64;
  for (int i = t; i < 4096; i += 256) {
    int cc = i >> 6, ff = i & 63;
    wT[ff * 68 + cc] = weight[i];
  }
  __syncthreads();

  const int f  = t >> 2;
  const int ns = (t & 3) * 16;

  float wr[64];
#pragma unroll
  for (int j = 0; j < 16; ++j) {
    float4 w4 = *(const float4*)&wT[f * 68 + 4 * j];
    wr[4*j] = w4.x; wr[4*j+1] = w4.y; wr[4*j+2] = w4.z; wr[4*j+3] = w4.w;
  }

  uint32_t outd[4];
#pragma unroll
  for (int i4 = 0; i4 < 4; ++i4) {
    float vb[4];
#pragma unroll
    for (int ii = 0; ii < 4; ++ii) {
      int n = n0 + ns + i4 * 4 + ii;
      const float4* xr = (const float4*)(x + (size_t)n * 64);
      float acc = 0.f;
#pragma unroll
      for (int j = 0; j < 16; ++j) {
        float4 xv = xr[j];
        acc += xv.x * wr[4*j] + xv.y * wr[4*j+1] + xv.z * wr[4*j+2] + xv.w * wr[4*j+3];
      }
      vb[ii] = 64.f * rsqrtf(rowsum[n]) * acc;
    }
    outd[i4] = pk4(vb[0], vb[1], vb[2], vb[3]);
  }
  uint4 v; v.x = outd[0]; v.y = outd[1]; v.z = outd[2]; v.w = outd[3];
  *(uint4*)(Zt + (size_t)f * NN + n0 + ns) = v;
}

// ---------------------------------------------------------------------------
// GEMM: D[m][f] = sum_k A[m][k]*B[f][k], fp8, F=64. Tile 128m x 128k,
// double-buffered LDS with depth-1 prefetch: STAGE(next) -> MFMA(cur) ->
// one __syncthreads() per k-tile (its vmcnt(0) lands exactly when the
// prefetched loads must be complete). XOR chunk swizzle (chunk c at slot
// c^(row&7)) -> near-conflict-free ds_read_b64 fragment reads.
// 256 thr / 4 waves; wave w owns m-rows [w*32,w*32+32) x all 64 f.
// Split-K partials (fp32) to Out + blockIdx.y*M*64.
// ---------------------------------------------------------------------------
__global__ __launch_bounds__(256) void k_gemm2(
    const uint8_t* __restrict__ A,   // [M][K] fp8
    const uint8_t* __restrict__ B,   // [64][K] fp8
    float* __restrict__ Out,
    int M, int K, int kchunk)
{
  __shared__ uint8_t Al[2][128 * 128];
  __shared__ uint8_t Bl[2][64 * 128];

  const int t    = threadIdx.x;
  const int lane = t & 63;
  const int wv   = t >> 6;
  const int m0   = blockIdx.x * 128;
  const int k0   = blockIdx.y * kchunk;
  const int iters = kchunk >> 7;        // BK = 128

  const int r = lane & 15;
  const int q = lane >> 4;

  // loader mapping: per instr, wave covers 8 rows x 8 chunks (16B each);
  // LDS dest = wave-uniform base + lane*16 (linear), global chunk XOR'd.
  const int lr = lane >> 3;     // row within 8-row group
  const int sl = lane & 7;      // LDS chunk slot within row

  const uint8_t* aptr[4];
  const uint8_t* bptr[2];
  uint32_t aoff[4];             // wave-uniform LDS byte offsets
  uint32_t boff[2];
#pragma unroll
  for (int i = 0; i < 4; ++i) {
    int ga = i * 4 + wv;                 // 8-row group 0..15
    int rA = ga * 8 + lr;
    int c  = sl ^ (rA & 7);
    aptr[i] = A + (size_t)(m0 + rA) * K + k0 + c * 16;
    aoff[i] = ga * 1024;
  }
#pragma unroll
  for (int i = 0; i < 2; ++i) {
    int gb = i * 4 + wv;                 // 8-row group 0..7
    int rB = gb * 8 + lr;
    int c  = sl ^ (rB & 7);
    bptr[i] = B + (size_t)rB * K + k0 + c * 16;
    boff[i] = gb * 1024;
  }

  v4f acc[2][4];
#pragma unroll
  for (int mt = 0; mt < 2; ++mt)
#pragma unroll
    for (int ft = 0; ft < 4; ++ft)
      acc[mt][ft] = (v4f){0.f, 0.f, 0.f, 0.f};

  // prologue: stage tile 0 into buffer 0
#pragma unroll
  for (int i = 0; i < 4; ++i) gl_lds16(aptr[i], &Al[0][aoff[i]]);
#pragma unroll
  for (int i = 0; i < 2; ++i) gl_lds16(bptr[i], &Bl[0][boff[i]]);
  __syncthreads();

  int cur = 0;
  for (int kt = 0; kt < iters; ++kt) {
    if (kt + 1 < iters) {                // depth-1 prefetch into buf^1
      const size_t ko = (size_t)(kt + 1) * 128;
#pragma unroll
      for (int i = 0; i < 4; ++i) gl_lds16(aptr[i] + ko, &Al[cur ^ 1][aoff[i]]);
#pragma unroll
      for (int i = 0; i < 2; ++i) gl_lds16(bptr[i] + ko, &Bl[cur ^ 1][boff[i]]);
    }
    const uint8_t* Ab = Al[cur];
    const uint8_t* Bb = Bl[cur];
#pragma unroll
    for (int ks = 0; ks < 4; ++ks) {
      const int ch = ks * 2 + (q >> 1);
      const int h8 = (q & 1) * 8;
      long bfr[4], afr[2];
#pragma unroll
      for (int ft = 0; ft < 4; ++ft) {
        int rb = ft * 16 + r;
        bfr[ft] = *(const long*)&Bb[rb * 128 + ((ch ^ (rb & 7)) * 16) + h8];
      }
#pragma unroll
      for (int mt = 0; mt < 2; ++mt) {
        int ra = wv * 32 + mt * 16 + r;
        afr[mt] = *(const long*)&Ab[ra * 128 + ((ch ^ (ra & 7)) * 16) + h8];
      }
#pragma unroll
      for (int mt = 0; mt < 2; ++mt)
#pragma unroll
        for (int ft = 0; ft < 4; ++ft)
          acc[mt][ft] = __builtin_amdgcn_mfma_f32_16x16x32_fp8_fp8(
              afr[mt], bfr[ft], acc[mt][ft], 0, 0, 0);
    }
    __syncthreads();                     // drains prefetch (vmcnt 0) + releases buf
    cur ^= 1;
  }

  float* U = Out + (size_t)blockIdx.y * M * 64;
#pragma unroll
  for (int mt = 0; mt < 2; ++mt)
#pragma unroll
    for (int ft = 0; ft < 4; ++ft)
#pragma unroll
      for (int i = 0; i < 4; ++i)
        U[(size_t)(m0 + wv * 32 + mt * 16 + 4 * q + i) * 64 + ft * 16 + r] =
            acc[mt][ft][i];
}

// ---------------------------------------------------------------------------
// K4: Yt[f][e] = fp8( 128 * W[e]/colsum[e] * sum_{p<16} Upart[p][e][f] )
// ---------------------------------------------------------------------------
__global__ __launch_bounds__(256) void k_y(
    const float* __restrict__ Upart,
    const float* __restrict__ W,
    const float* __restrict__ colsum,
    uint8_t* __restrict__ Yt)
{
  __shared__ uint8_t TY[64 * 80];
  const int t  = threadIdx.x;
  const int e0 = blockIdx.x * 64;
  const int el = t >> 2;
  const int c4 = (t & 3) * 16;
  const int e  = e0 + el;
  const float sc = 128.f * W[e] / colsum[e];

  float s[16];
#pragma unroll
  for (int j = 0; j < 16; ++j) s[j] = 0.f;
  for (int p = 0; p < 16; ++p) {
    const float4* u = (const float4*)(Upart + ((size_t)p * EE + e) * 64 + c4);
#pragma unroll
    for (int j = 0; j < 4; ++j) {
      float4 a = u[j];
      s[4*j+0] += a.x; s[4*j+1] += a.y; s[4*j+2] += a.z; s[4*j+3] += a.w;
    }
  }
#pragma unroll
  for (int j = 0; j < 4; ++j) {
    uint32_t dw = pk4(sc * s[4*j], sc * s[4*j+1], sc * s[4*j+2], sc * s[4*j+3]);
    TY[(size_t)(c4 + 4 * j + 0) * 80 + el] = (uint8_t)(dw);
    TY[(size_t)(c4 + 4 * j + 1) * 80 + el] = (uint8_t)(dw >> 8);
    TY[(size_t)(c4 + 4 * j + 2) * 80 + el] = (uint8_t)(dw >> 16);
    TY[(size_t)(c4 + 4 * j + 3) * 80 + el] = (uint8_t)(dw >> 24);
  }
  __syncthreads();
  const int f  = t >> 2;
  const int ec = (t & 3) * 16;
  uint4 v = *(const uint4*)&TY[(size_t)f * 80 + ec];
  *(uint4*)(Yt + (size_t)f * EE + e0 + ec) = v;
}

// ---------------------------------------------------------------------------
// K6: out[n][f] = rsqrt(rowsum[n]) * (sum_{p<8} Vpart[p][n][f]) / 8192 + bias
// ---------------------------------------------------------------------------
__global__ __launch_bounds__(256) void k_out(
    const float* __restrict__ Vpart,
    const float* __restrict__ rowsum,
    const float* __restrict__ bias,
    float* __restrict__ out)
{
  const int t  = threadIdx.x;
  const int n  = blockIdx.x * 64 + (t >> 2);
  const int c4 = (t & 3) * 16;
  float s[16];
#pragma unroll
  for (int j = 0; j < 16; ++j) s[j] = 0.f;
#pragma unroll
  for (int p = 0; p < 8; ++p) {
    const float4* v = (const float4*)(Vpart + ((size_t)p * NN + n) * 64 + c4);
#pragma unroll
    for (int j = 0; j < 4; ++j) {
      float4 a = v[j];
      s[4*j+0] += a.x; s[4*j+1] += a.y; s[4*j+2] += a.z; s[4*j+3] += a.w;
    }
  }
  const float dv = rsqrtf(rowsum[n]) * (1.f / 8192.f);
  float4* o = (float4*)(out + (size_t)n * 64 + c4);
#pragma unroll
  for (int j = 0; j < 4; ++j) {
    float4 bb = *(const float4*)(bias + c4 + 4 * j);
    float4 rr;
    rr.x = s[4*j+0] * dv + bb.x;
    rr.y = s[4*j+1] * dv + bb.y;
    rr.z = s[4*j+2] * dv + bb.z;
    rr.w = s[4*j+3] * dv + bb.w;
    o[j] = rr;
  }
}

// ---------------------------------------------------------------------------
extern "C" void kernel_launch(void* const* d_in, const int* in_sizes, int n_in,
                              void* d_out, int out_size, void* d_ws, size_t ws_size,
                              hipStream_t stream) {
  const float* x      = (const float*)d_in[0];
  const float* H      = (const float*)d_in[1];
  const float* W      = (const float*)d_in[2];
  const float* weight = (const float*)d_in[3];
  const float* bias   = (const float*)d_in[4];
  float* out          = (float*)d_out;

  uint8_t* ws    = (uint8_t*)d_ws;
  uint8_t* Hn8   = ws;                                   // 128 MiB
  uint8_t* H8T   = ws + (size_t)NN * EE;                 // 128 MiB
  float*  rowsum = (float*)(ws + 2ull * NN * EE);        // 64 KiB
  float*  colsum = rowsum + NN;                          // 32 KiB
  uint8_t* Zt    = (uint8_t*)(colsum + EE);              // 1 MiB
  uint8_t* Yt    = Zt + (size_t)64 * NN;                 // 0.5 MiB
  float*  Upart  = (float*)(Yt + (size_t)64 * EE);       // 16 parts x 2 MiB
  float*  Vpart  = Upart + 16ull * EE * 64;              // 8 parts x 4 MiB

  hipMemsetAsync(rowsum, 0, (NN + EE) * sizeof(float), stream);

  k_prep_h<<<dim3(32, 256), 256, 0, stream>>>(H, Hn8, H8T, rowsum, colsum);
  k_z<<<dim3(256), 256, 0, stream>>>(x, weight, rowsum, Zt);
  // pass B: U[e][f] = sum_n H8T[e][n] * Zt[f][n]; M=EE, K=NN, split-K=16
  k_gemm2<<<dim3(64, 16), 256, 0, stream>>>(H8T, Zt, Upart, EE, NN, NN / 16);
  k_y<<<dim3(128), 256, 0, stream>>>(Upart, W, colsum, Yt);
  // pass C: V[n][f] = sum_e Hn8[n][e] * Yt[f][e]; M=NN, K=EE, split-K=8
  k_gemm2<<<dim3(128, 8), 256, 0, stream>>>(Hn8, Yt, Vpart, NN, EE, EE / 8);
  k_out<<<dim3(256), 256, 0, stream>>>(Vpart, rowsum, bias, out);
}